// Round 1
// baseline (1828.345 us; speedup 1.0000x reference)
//
#include <hip/hip_runtime.h>

#define F 128
#define NCLS 10
#define NG 64

// ---------------- dual GEMM: Yl = X@Wl + bl, Yr = X@Wr + br ----------------
#define GR 32
__global__ __launch_bounds__(128) void dual_gemm(
    const float* __restrict__ X,
    const float* __restrict__ Wl, const float* __restrict__ bl,
    const float* __restrict__ Wr, const float* __restrict__ br,
    float* __restrict__ Yl, float* __restrict__ Yr, int nrows)
{
  __shared__ float Xs[GR][F];
  const int row0 = blockIdx.x * GR;
  const int t = threadIdx.x;  // 0..127, also the output column
  #pragma unroll
  for (int i = 0; i < GR; ++i) {
    int r = row0 + i;
    Xs[i][t] = (r < nrows) ? X[(size_t)r * F + t] : 0.0f;
  }
  __syncthreads();
  const int c = t;
  float accl[GR], accr[GR];
  const float bl0 = bl[c], br0 = br[c];
  #pragma unroll
  for (int r = 0; r < GR; ++r) { accl[r] = bl0; accr[r] = br0; }
  for (int k4 = 0; k4 < F / 4; ++k4) {
    float wl[4], wr[4];
    #pragma unroll
    for (int j = 0; j < 4; ++j) {
      wl[j] = Wl[(k4 * 4 + j) * F + c];
      wr[j] = Wr[(k4 * 4 + j) * F + c];
    }
    #pragma unroll
    for (int r = 0; r < GR; ++r) {
      float4 xv = *reinterpret_cast<const float4*>(&Xs[r][k4 * 4]);
      accl[r] = fmaf(xv.x, wl[0], accl[r]);
      accl[r] = fmaf(xv.y, wl[1], accl[r]);
      accl[r] = fmaf(xv.z, wl[2], accl[r]);
      accl[r] = fmaf(xv.w, wl[3], accl[r]);
      accr[r] = fmaf(xv.x, wr[0], accr[r]);
      accr[r] = fmaf(xv.y, wr[1], accr[r]);
      accr[r] = fmaf(xv.z, wr[2], accr[r]);
      accr[r] = fmaf(xv.w, wr[3], accr[r]);
    }
  }
  #pragma unroll
  for (int r = 0; r < GR; ++r) {
    int rr = row0 + r;
    if (rr < nrows) {
      Yl[(size_t)rr * F + c] = accl[r];
      Yr[(size_t)rr * F + c] = accr[r];
    }
  }
}

// ---------------- CSR build ----------------
__global__ void k_count(const int* __restrict__ dst, int* __restrict__ cnt, int E_) {
  int e = blockIdx.x * blockDim.x + threadIdx.x;
  if (e < E_) atomicAdd(&cnt[dst[e]], 1);
}

__global__ __launch_bounds__(256) void k_scan1(const int* __restrict__ in,
                                               int* __restrict__ out,
                                               int* __restrict__ bsum, int n) {
  __shared__ int lds[256];
  int b = blockIdx.x, t = threadIdx.x;
  int base = b * 1024 + t * 4;
  int v[4]; int s = 0;
  #pragma unroll
  for (int j = 0; j < 4; ++j) { v[j] = (base + j < n) ? in[base + j] : 0; s += v[j]; }
  lds[t] = s;
  __syncthreads();
  for (int d = 1; d < 256; d <<= 1) {
    int x = (t >= d) ? lds[t - d] : 0;
    __syncthreads();
    lds[t] += x;
    __syncthreads();
  }
  int incl = lds[t];
  int excl = incl - s;
  if (t == 255) bsum[b] = incl;
  int run = excl;
  #pragma unroll
  for (int j = 0; j < 4; ++j) {
    if (base + j < n) out[base + j] = run;
    run += v[j];
  }
}

__global__ void k_scan2(int* bsum, int nb) {
  if (threadIdx.x == 0 && blockIdx.x == 0) {
    int run = 0;
    for (int i = 0; i < nb; ++i) { int v = bsum[i]; bsum[i] = run; run += v; }
  }
}

__global__ void k_scan3(int* __restrict__ rowptr, const int* __restrict__ bsum,
                        int n, int total) {
  int i = blockIdx.x * blockDim.x + threadIdx.x;
  if (i < n) rowptr[i] += bsum[i >> 10];
  if (i == 0) rowptr[n] = total;
}

__global__ void k_fill(const int* __restrict__ src, const int* __restrict__ dst,
                       int* __restrict__ cursor, int* __restrict__ srclist, int E_) {
  int e = blockIdx.x * blockDim.x + threadIdx.x;
  if (e < E_) {
    int d = dst[e];
    int pos = atomicAdd(&cursor[d], 1);
    srclist[pos] = src[e];
  }
}

// ---------------- fused GATv2 conv1 (8 heads of 16ch) + ELU ----------------
__global__ __launch_bounds__(256) void gat_conv1(
    const float* __restrict__ xl, const float* __restrict__ xr,
    const int* __restrict__ rowptr, const int* __restrict__ srclist,
    const float* __restrict__ att, const float* __restrict__ bias,
    float* __restrict__ h1, int nnodes)
{
  int wid = (blockIdx.x * blockDim.x + threadIdx.x) >> 6;
  int lane = threadIdx.x & 63;
  if (wid >= nnodes) return;
  const int n = wid;
  const int c0 = lane * 2;
  const float2 xrv = *reinterpret_cast<const float2*>(&xr[(size_t)n * F + c0]);
  const float a0 = att[c0], a1 = att[c0 + 1];
  float den = 0.f, acc0 = 0.f, acc1 = 0.f;
  const int beg = rowptr[n], end = rowptr[n + 1];
#define BODY1(sidx) { \
    const float2 xlv = *reinterpret_cast<const float2*>(&xl[(size_t)(sidx) * F + c0]); \
    float t0 = xlv.x + xrv.x; t0 = t0 > 0.f ? t0 : 0.2f * t0; \
    float t1 = xlv.y + xrv.y; t1 = t1 > 0.f ? t1 : 0.2f * t1; \
    float part = t0 * a0 + t1 * a1; \
    part += __shfl_xor(part, 1); \
    part += __shfl_xor(part, 2); \
    part += __shfl_xor(part, 4); \
    float p = __expf(part); \
    den += p; acc0 += p * xlv.x; acc1 += p * xlv.y; }
  BODY1(n)
  for (int i = beg; i < end; ++i) { int s = srclist[i]; BODY1(s) }
#undef BODY1
  float inv = 1.0f / den;
  float o0 = acc0 * inv + bias[c0];
  float o1 = acc1 * inv + bias[c0 + 1];
  o0 = o0 > 0.f ? o0 : (__expf(o0) - 1.0f);
  o1 = o1 > 0.f ? o1 : (__expf(o1) - 1.0f);
  *reinterpret_cast<float2*>(&h1[(size_t)n * F + c0]) = make_float2(o0, o1);
}

// ---------------- fused GATv2 conv2 (1 head of 128ch) + ELU + mean-pool ----
__global__ __launch_bounds__(256) void gat_conv2_pool(
    const float* __restrict__ xl, const float* __restrict__ xr,
    const int* __restrict__ rowptr, const int* __restrict__ srclist,
    const float* __restrict__ att, const float* __restrict__ bias,
    const int* __restrict__ batch,
    float* __restrict__ sums, float* __restrict__ gcnt, int nnodes)
{
  int wid = (blockIdx.x * blockDim.x + threadIdx.x) >> 6;
  int lane = threadIdx.x & 63;
  if (wid >= nnodes) return;
  const int n = wid;
  const int c0 = lane * 2;
  const float2 xrv = *reinterpret_cast<const float2*>(&xr[(size_t)n * F + c0]);
  const float a0 = att[c0], a1 = att[c0 + 1];
  float den = 0.f, acc0 = 0.f, acc1 = 0.f;
  const int beg = rowptr[n], end = rowptr[n + 1];
#define BODY2(sidx) { \
    const float2 xlv = *reinterpret_cast<const float2*>(&xl[(size_t)(sidx) * F + c0]); \
    float t0 = xlv.x + xrv.x; t0 = t0 > 0.f ? t0 : 0.2f * t0; \
    float t1 = xlv.y + xrv.y; t1 = t1 > 0.f ? t1 : 0.2f * t1; \
    float part = t0 * a0 + t1 * a1; \
    part += __shfl_xor(part, 1); \
    part += __shfl_xor(part, 2); \
    part += __shfl_xor(part, 4); \
    part += __shfl_xor(part, 8); \
    part += __shfl_xor(part, 16); \
    part += __shfl_xor(part, 32); \
    float p = __expf(part); \
    den += p; acc0 += p * xlv.x; acc1 += p * xlv.y; }
  BODY2(n)
  for (int i = beg; i < end; ++i) { int s = srclist[i]; BODY2(s) }
#undef BODY2
  float inv = 1.0f / den;
  float o0 = acc0 * inv + bias[c0];
  float o1 = acc1 * inv + bias[c0 + 1];
  o0 = o0 > 0.f ? o0 : (__expf(o0) - 1.0f);
  o1 = o1 > 0.f ? o1 : (__expf(o1) - 1.0f);
  int g = batch[n];
  atomicAdd(&sums[g * F + c0], o0);
  atomicAdd(&sums[g * F + c0 + 1], o1);
  if (lane == 0) atomicAdd(&gcnt[g], 1.0f);
}

// ---------------- final: out = (sums/cnt) @ W3 + b3 ----------------
__global__ void k_final(const float* __restrict__ sums, const float* __restrict__ gcnt,
                        const float* __restrict__ W3, const float* __restrict__ b3,
                        float* __restrict__ out)
{
  int t = blockIdx.x * blockDim.x + threadIdx.x;
  if (t >= NG * NCLS) return;
  int g = t / NCLS, k = t % NCLS;
  float acc = 0.f;
  for (int cc = 0; cc < F; ++cc) acc = fmaf(sums[g * F + cc], W3[cc * NCLS + k], acc);
  float cv = gcnt[g]; cv = cv > 1.0f ? cv : 1.0f;
  out[t] = acc / cv + b3[k];
}

extern "C" void kernel_launch(void* const* d_in, const int* in_sizes, int n_in,
                              void* d_out, int out_size, void* d_ws, size_t ws_size,
                              hipStream_t stream)
{
  const float* x     = (const float*)d_in[0];
  const int*   ei    = (const int*)d_in[1];
  const int*   batch = (const int*)d_in[2];
  const float* W1l = (const float*)d_in[3];
  const float* b1l = (const float*)d_in[4];
  const float* W1r = (const float*)d_in[5];
  const float* b1r = (const float*)d_in[6];
  const float* att1  = (const float*)d_in[7];
  const float* bias1 = (const float*)d_in[8];
  const float* W2l = (const float*)d_in[9];
  const float* b2l = (const float*)d_in[10];
  const float* W2r = (const float*)d_in[11];
  const float* b2r = (const float*)d_in[12];
  const float* att2  = (const float*)d_in[13];
  const float* bias2 = (const float*)d_in[14];
  const float* W3 = (const float*)d_in[15];
  const float* b3 = (const float*)d_in[16];

  const int Nn = in_sizes[0] / F;
  const int Ee = in_sizes[1] / 2;
  const int* srcp = ei;
  const int* dstp = ei + Ee;

  char* ws = (char*)d_ws;
  size_t off = 0;
  auto alloc = [&](size_t bytes) -> void* {
    void* p = ws + off;
    off = (off + bytes + 255) & ~size_t(255);
    return p;
  };
  float* xl      = (float*)alloc((size_t)Nn * F * 4);
  float* xr      = (float*)alloc((size_t)Nn * F * 4);
  float* h1      = (float*)alloc((size_t)Nn * F * 4);
  int*   cnt     = (int*)alloc((size_t)Nn * 4);          // count, later cursor
  int*   rowptr  = (int*)alloc((size_t)(Nn + 1) * 4);
  int*   srclist = (int*)alloc((size_t)Ee * 4);
  float* sums    = (float*)alloc((size_t)(NG * F + NG) * 4);  // sums + gcnt
  float* gcnt    = sums + NG * F;
  int*   bsum    = (int*)alloc(1024);

  hipMemsetAsync(cnt, 0, (size_t)Nn * 4, stream);
  hipMemsetAsync(sums, 0, (size_t)(NG * F + NG) * 4, stream);

  const int TB = 256;
  k_count<<<(Ee + TB - 1) / TB, TB, 0, stream>>>(dstp, cnt, Ee);
  int nb = (Nn + 1023) / 1024;
  k_scan1<<<nb, 256, 0, stream>>>(cnt, rowptr, bsum, Nn);
  k_scan2<<<1, 64, 0, stream>>>(bsum, nb);
  k_scan3<<<(Nn + TB - 1) / TB, TB, 0, stream>>>(rowptr, bsum, Nn, Ee);
  hipMemcpyAsync(cnt, rowptr, (size_t)Nn * 4, hipMemcpyDeviceToDevice, stream);
  k_fill<<<(Ee + TB - 1) / TB, TB, 0, stream>>>(srcp, dstp, cnt, srclist, Ee);

  dual_gemm<<<(Nn + GR - 1) / GR, 128, 0, stream>>>(x, W1l, b1l, W1r, b1r, xl, xr, Nn);
  gat_conv1<<<(Nn + 3) / 4, 256, 0, stream>>>(xl, xr, rowptr, srclist, att1, bias1, h1, Nn);
  dual_gemm<<<(Nn + GR - 1) / GR, 128, 0, stream>>>(h1, W2l, b2l, W2r, b2r, xl, xr, Nn);
  gat_conv2_pool<<<(Nn + 3) / 4, 256, 0, stream>>>(xl, xr, rowptr, srclist, att2, bias2,
                                                   batch, sums, gcnt, Nn);
  k_final<<<(NG * NCLS + 255) / 256, 256, 0, stream>>>(sums, gcnt, W3, b3, (float*)d_out);
}

// Round 2
// 1370.650 us; speedup vs baseline: 1.3339x; 1.3339x over previous
//
#include <hip/hip_runtime.h>

#define F 128
#define NCLS 10
#define NG 64

// ---------------- dual GEMM: Yl = X@Wl + bl, Yr = X@Wr + br ----------------
#define GR 32
__global__ __launch_bounds__(128) void dual_gemm(
    const float* __restrict__ X,
    const float* __restrict__ Wl, const float* __restrict__ bl,
    const float* __restrict__ Wr, const float* __restrict__ br,
    float* __restrict__ Yl, float* __restrict__ Yr, int nrows)
{
  __shared__ float Xs[GR][F];
  const int row0 = blockIdx.x * GR;
  const int t = threadIdx.x;  // 0..127, also the output column
  #pragma unroll
  for (int i = 0; i < GR; ++i) {
    int r = row0 + i;
    Xs[i][t] = (r < nrows) ? X[(size_t)r * F + t] : 0.0f;
  }
  __syncthreads();
  const int c = t;
  float accl[GR], accr[GR];
  const float bl0 = bl[c], br0 = br[c];
  #pragma unroll
  for (int r = 0; r < GR; ++r) { accl[r] = bl0; accr[r] = br0; }
  for (int k4 = 0; k4 < F / 4; ++k4) {
    float wl[4], wr[4];
    #pragma unroll
    for (int j = 0; j < 4; ++j) {
      wl[j] = Wl[(k4 * 4 + j) * F + c];
      wr[j] = Wr[(k4 * 4 + j) * F + c];
    }
    #pragma unroll
    for (int r = 0; r < GR; ++r) {
      float4 xv = *reinterpret_cast<const float4*>(&Xs[r][k4 * 4]);
      accl[r] = fmaf(xv.x, wl[0], accl[r]);
      accl[r] = fmaf(xv.y, wl[1], accl[r]);
      accl[r] = fmaf(xv.z, wl[2], accl[r]);
      accl[r] = fmaf(xv.w, wl[3], accl[r]);
      accr[r] = fmaf(xv.x, wr[0], accr[r]);
      accr[r] = fmaf(xv.y, wr[1], accr[r]);
      accr[r] = fmaf(xv.z, wr[2], accr[r]);
      accr[r] = fmaf(xv.w, wr[3], accr[r]);
    }
  }
  #pragma unroll
  for (int r = 0; r < GR; ++r) {
    int rr = row0 + r;
    if (rr < nrows) {
      Yl[(size_t)rr * F + c] = accl[r];
      Yr[(size_t)rr * F + c] = accr[r];
    }
  }
}

// ---------------- CSR build ----------------
__global__ void k_count(const int* __restrict__ dst, int* __restrict__ cnt, int E_) {
  int e = blockIdx.x * blockDim.x + threadIdx.x;
  if (e < E_) atomicAdd(&cnt[dst[e]], 1);
}

__global__ __launch_bounds__(256) void k_scan1(const int* __restrict__ in,
                                               int* __restrict__ out,
                                               int* __restrict__ bsum, int n) {
  __shared__ int lds[256];
  int b = blockIdx.x, t = threadIdx.x;
  int base = b * 1024 + t * 4;
  int v[4]; int s = 0;
  #pragma unroll
  for (int j = 0; j < 4; ++j) { v[j] = (base + j < n) ? in[base + j] : 0; s += v[j]; }
  lds[t] = s;
  __syncthreads();
  for (int d = 1; d < 256; d <<= 1) {
    int x = (t >= d) ? lds[t - d] : 0;
    __syncthreads();
    lds[t] += x;
    __syncthreads();
  }
  int incl = lds[t];
  int excl = incl - s;
  if (t == 255) bsum[b] = incl;
  int run = excl;
  #pragma unroll
  for (int j = 0; j < 4; ++j) {
    if (base + j < n) out[base + j] = run;
    run += v[j];
  }
}

__global__ void k_scan2(int* bsum, int nb) {
  if (threadIdx.x == 0 && blockIdx.x == 0) {
    int run = 0;
    for (int i = 0; i < nb; ++i) { int v = bsum[i]; bsum[i] = run; run += v; }
  }
}

__global__ void k_scan3(int* __restrict__ rowptr, const int* __restrict__ bsum,
                        int n, int total) {
  int i = blockIdx.x * blockDim.x + threadIdx.x;
  if (i < n) rowptr[i] += bsum[i >> 10];
  if (i == 0) rowptr[n] = total;
}

__global__ void k_fill(const int* __restrict__ src, const int* __restrict__ dst,
                       int* __restrict__ cursor, int* __restrict__ srclist,
                       int* __restrict__ dstlist, int E_) {
  int e = blockIdx.x * blockDim.x + threadIdx.x;
  if (e < E_) {
    int d = dst[e];
    int pos = atomicAdd(&cursor[d], 1);
    srclist[pos] = src[e];
    dstlist[pos] = d;
  }
}

// ---------------- edge-parallel scores, conv1 (8 heads) -------------------
// slot in [0, E): CSR edge slot.  slot in [E, E+N): self-loop of node slot-E.
// Each 32-lane half-wave handles one slot: 32 lanes x float4 = 128 ch.
__global__ __launch_bounds__(256) void score1(
    const float* __restrict__ xl, const float* __restrict__ xr,
    const int* __restrict__ srclist, const int* __restrict__ dstlist,
    const float* __restrict__ att, float* __restrict__ p1, int E_, int S_)
{
  int wid = (blockIdx.x * blockDim.x + threadIdx.x) >> 6;
  int lane = threadIdx.x & 63;
  int slot = wid * 2 + (lane >> 5);
  if (slot >= S_) return;
  int l = lane & 31;
  int src, dstn;
  if (slot < E_) { src = srclist[slot]; dstn = dstlist[slot]; }
  else { src = slot - E_; dstn = src; }
  int c0 = l * 4;
  float4 xlv = *reinterpret_cast<const float4*>(&xl[(size_t)src * F + c0]);
  float4 xrv = *reinterpret_cast<const float4*>(&xr[(size_t)dstn * F + c0]);
  float4 av  = *reinterpret_cast<const float4*>(&att[c0]);
  float t, s = 0.0f;
  t = xlv.x + xrv.x; t = t > 0.f ? t : 0.2f * t; s = fmaf(t, av.x, s);
  t = xlv.y + xrv.y; t = t > 0.f ? t : 0.2f * t; s = fmaf(t, av.y, s);
  t = xlv.z + xrv.z; t = t > 0.f ? t : 0.2f * t; s = fmaf(t, av.z, s);
  t = xlv.w + xrv.w; t = t > 0.f ? t : 0.2f * t; s = fmaf(t, av.w, s);
  // reduce over the 4 lanes of each head (16 ch)
  s += __shfl_xor(s, 1);
  s += __shfl_xor(s, 2);
  if ((l & 3) == 0) p1[(size_t)slot * 8 + (l >> 2)] = __expf(s);
}

// ---------------- edge-parallel scores, conv2 (1 head, 128 ch) ------------
__global__ __launch_bounds__(256) void score2(
    const float* __restrict__ xl, const float* __restrict__ xr,
    const int* __restrict__ srclist, const int* __restrict__ dstlist,
    const float* __restrict__ att, float* __restrict__ p2, int E_, int S_)
{
  int wid = (blockIdx.x * blockDim.x + threadIdx.x) >> 6;
  int lane = threadIdx.x & 63;
  int slot = wid * 2 + (lane >> 5);
  if (slot >= S_) return;
  int l = lane & 31;
  int src, dstn;
  if (slot < E_) { src = srclist[slot]; dstn = dstlist[slot]; }
  else { src = slot - E_; dstn = src; }
  int c0 = l * 4;
  float4 xlv = *reinterpret_cast<const float4*>(&xl[(size_t)src * F + c0]);
  float4 xrv = *reinterpret_cast<const float4*>(&xr[(size_t)dstn * F + c0]);
  float4 av  = *reinterpret_cast<const float4*>(&att[c0]);
  float t, s = 0.0f;
  t = xlv.x + xrv.x; t = t > 0.f ? t : 0.2f * t; s = fmaf(t, av.x, s);
  t = xlv.y + xrv.y; t = t > 0.f ? t : 0.2f * t; s = fmaf(t, av.y, s);
  t = xlv.z + xrv.z; t = t > 0.f ? t : 0.2f * t; s = fmaf(t, av.z, s);
  t = xlv.w + xrv.w; t = t > 0.f ? t : 0.2f * t; s = fmaf(t, av.w, s);
  s += __shfl_xor(s, 1);
  s += __shfl_xor(s, 2);
  s += __shfl_xor(s, 4);
  s += __shfl_xor(s, 8);
  s += __shfl_xor(s, 16);
  if (l == 0) p2[slot] = __expf(s);
}

// ---------------- node aggregation conv1 (shuffle-free) + ELU -------------
__global__ __launch_bounds__(256) void node_agg1(
    const float* __restrict__ xl, const int* __restrict__ rowptr,
    const int* __restrict__ srclist, const float* __restrict__ p1,
    const float* __restrict__ bias, float* __restrict__ out, int Nn, int E_)
{
  int wid = (blockIdx.x * blockDim.x + threadIdx.x) >> 6;
  int lane = threadIdx.x & 63;
  if (wid >= Nn) return;
  const int n = wid;
  const int c0 = lane * 2;
  const int h = lane >> 3;
  float2 xls = *reinterpret_cast<const float2*>(&xl[(size_t)n * F + c0]);
  float pv = p1[((size_t)(E_ + n)) * 8 + h];   // self-loop
  float den = pv, a0 = pv * xls.x, a1 = pv * xls.y;
  const int beg = rowptr[n], end = rowptr[n + 1];
  #pragma unroll 2
  for (int i = beg; i < end; ++i) {
    int s = srclist[i];
    float pe = p1[(size_t)i * 8 + h];
    float2 xv = *reinterpret_cast<const float2*>(&xl[(size_t)s * F + c0]);
    den += pe;
    a0 = fmaf(pe, xv.x, a0);
    a1 = fmaf(pe, xv.y, a1);
  }
  float inv = 1.0f / den;
  float o0 = a0 * inv + bias[c0];
  float o1 = a1 * inv + bias[c0 + 1];
  o0 = o0 > 0.f ? o0 : (__expf(o0) - 1.0f);
  o1 = o1 > 0.f ? o1 : (__expf(o1) - 1.0f);
  *reinterpret_cast<float2*>(&out[(size_t)n * F + c0]) = make_float2(o0, o1);
}

// ---------------- node aggregation conv2 (shuffle-free) + ELU -------------
__global__ __launch_bounds__(256) void node_agg2(
    const float* __restrict__ xl, const int* __restrict__ rowptr,
    const int* __restrict__ srclist, const float* __restrict__ p2,
    const float* __restrict__ bias, float* __restrict__ out, int Nn, int E_)
{
  int wid = (blockIdx.x * blockDim.x + threadIdx.x) >> 6;
  int lane = threadIdx.x & 63;
  if (wid >= Nn) return;
  const int n = wid;
  const int c0 = lane * 2;
  float2 xls = *reinterpret_cast<const float2*>(&xl[(size_t)n * F + c0]);
  float pv = p2[E_ + n];                       // self-loop
  float den = pv, a0 = pv * xls.x, a1 = pv * xls.y;
  const int beg = rowptr[n], end = rowptr[n + 1];
  #pragma unroll 2
  for (int i = beg; i < end; ++i) {
    int s = srclist[i];
    float pe = p2[i];
    float2 xv = *reinterpret_cast<const float2*>(&xl[(size_t)s * F + c0]);
    den += pe;
    a0 = fmaf(pe, xv.x, a0);
    a1 = fmaf(pe, xv.y, a1);
  }
  float inv = 1.0f / den;
  float o0 = a0 * inv + bias[c0];
  float o1 = a1 * inv + bias[c0 + 1];
  o0 = o0 > 0.f ? o0 : (__expf(o0) - 1.0f);
  o1 = o1 > 0.f ? o1 : (__expf(o1) - 1.0f);
  *reinterpret_cast<float2*>(&out[(size_t)n * F + c0]) = make_float2(o0, o1);
}

// ---------------- per-graph mean pool (batch is sorted) -------------------
__global__ __launch_bounds__(256) void k_pool(
    const float* __restrict__ h2, const int* __restrict__ batch,
    float* __restrict__ pooled, int Nn)
{
  int g = blockIdx.x;
  __shared__ int sb[2];
  if (threadIdx.x < 2) {
    int target = g + (int)threadIdx.x;
    int lo = 0, hi = Nn;
    while (lo < hi) { int mid = (lo + hi) >> 1; if (batch[mid] < target) lo = mid + 1; else hi = mid; }
    sb[threadIdx.x] = lo;
  }
  __syncthreads();
  int lo = sb[0], hi = sb[1];
  int c = threadIdx.x & 127, half = threadIdx.x >> 7;
  float acc = 0.f;
  for (int n = lo + half; n < hi; n += 2) acc += h2[(size_t)n * F + c];
  __shared__ float red[256];
  red[threadIdx.x] = acc;
  __syncthreads();
  if (half == 0) {
    float tot = red[c] + red[c + 128];
    int cnt = hi - lo;
    pooled[g * F + c] = tot / (float)(cnt > 1 ? cnt : 1);
  }
}

// ---------------- final: out = pooled @ W3 + b3 ----------------
__global__ void k_final(const float* __restrict__ pooled,
                        const float* __restrict__ W3, const float* __restrict__ b3,
                        float* __restrict__ out)
{
  int t = blockIdx.x * blockDim.x + threadIdx.x;
  if (t >= NG * NCLS) return;
  int g = t / NCLS, k = t % NCLS;
  float acc = b3[k];
  for (int cc = 0; cc < F; ++cc) acc = fmaf(pooled[g * F + cc], W3[cc * NCLS + k], acc);
  out[t] = acc;
}

extern "C" void kernel_launch(void* const* d_in, const int* in_sizes, int n_in,
                              void* d_out, int out_size, void* d_ws, size_t ws_size,
                              hipStream_t stream)
{
  const float* x     = (const float*)d_in[0];
  const int*   ei    = (const int*)d_in[1];
  const int*   batch = (const int*)d_in[2];
  const float* W1l = (const float*)d_in[3];
  const float* b1l = (const float*)d_in[4];
  const float* W1r = (const float*)d_in[5];
  const float* b1r = (const float*)d_in[6];
  const float* att1  = (const float*)d_in[7];
  const float* bias1 = (const float*)d_in[8];
  const float* W2l = (const float*)d_in[9];
  const float* b2l = (const float*)d_in[10];
  const float* W2r = (const float*)d_in[11];
  const float* b2r = (const float*)d_in[12];
  const float* att2  = (const float*)d_in[13];
  const float* bias2 = (const float*)d_in[14];
  const float* W3 = (const float*)d_in[15];
  const float* b3 = (const float*)d_in[16];

  const int Nn = in_sizes[0] / F;
  const int Ee = in_sizes[1] / 2;
  const int Ss = Ee + Nn;   // edge slots + self-loop slots
  const int* srcp = ei;
  const int* dstp = ei + Ee;

  char* ws = (char*)d_ws;
  size_t off = 0;
  auto alloc = [&](size_t bytes) -> void* {
    void* p = ws + off;
    off = (off + bytes + 255) & ~size_t(255);
    return p;
  };
  float* xl      = (float*)alloc((size_t)Nn * F * 4);
  float* xr      = (float*)alloc((size_t)Nn * F * 4);
  float* h12     = (float*)alloc((size_t)Nn * F * 4);   // h1, then reused as h2
  float* p12     = (float*)alloc((size_t)Ss * 8 * 4);   // p1 [S][8]; p2 uses first S
  int*   cnt     = (int*)alloc((size_t)Nn * 4);         // count, later cursor
  int*   rowptr  = (int*)alloc((size_t)(Nn + 1) * 4);
  int*   srclist = (int*)alloc((size_t)Ee * 4);
  int*   dstlist = (int*)alloc((size_t)Ee * 4);
  float* pooled  = (float*)alloc((size_t)NG * F * 4);
  int*   bsum    = (int*)alloc(1024);

  hipMemsetAsync(cnt, 0, (size_t)Nn * 4, stream);

  const int TB = 256;
  // CSR build
  k_count<<<(Ee + TB - 1) / TB, TB, 0, stream>>>(dstp, cnt, Ee);
  int nb = (Nn + 1023) / 1024;
  k_scan1<<<nb, 256, 0, stream>>>(cnt, rowptr, bsum, Nn);
  k_scan2<<<1, 64, 0, stream>>>(bsum, nb);
  k_scan3<<<(Nn + TB - 1) / TB, TB, 0, stream>>>(rowptr, bsum, Nn, Ee);
  hipMemcpyAsync(cnt, rowptr, (size_t)Nn * 4, hipMemcpyDeviceToDevice, stream);
  k_fill<<<(Ee + TB - 1) / TB, TB, 0, stream>>>(srcp, dstp, cnt, srclist, dstlist, Ee);

  int score_blocks = ((Ss + 1) / 2 + 3) / 4;   // 2 slots/wave, 4 waves/block
  int node_blocks  = (Nn + 3) / 4;

  // conv1
  dual_gemm<<<(Nn + GR - 1) / GR, 128, 0, stream>>>(x, W1l, b1l, W1r, b1r, xl, xr, Nn);
  score1<<<score_blocks, 256, 0, stream>>>(xl, xr, srclist, dstlist, att1, p12, Ee, Ss);
  node_agg1<<<node_blocks, 256, 0, stream>>>(xl, rowptr, srclist, p12, bias1, h12, Nn, Ee);
  // conv2
  dual_gemm<<<(Nn + GR - 1) / GR, 128, 0, stream>>>(h12, W2l, b2l, W2r, b2r, xl, xr, Nn);
  score2<<<score_blocks, 256, 0, stream>>>(xl, xr, srclist, dstlist, att2, p12, Ee, Ss);
  node_agg2<<<node_blocks, 256, 0, stream>>>(xl, rowptr, srclist, p12, bias2, h12, Nn, Ee);
  // pool + head
  k_pool<<<NG, 256, 0, stream>>>(h12, batch, pooled, Nn);
  k_final<<<(NG * NCLS + 255) / 256, 256, 0, stream>>>(pooled, W3, b3, (float*)d_out);
}

// Round 5
// 1213.474 us; speedup vs baseline: 1.5067x; 1.1295x over previous
//
#include <hip/hip_runtime.h>

#define F 128
#define NCLS 10
#define NG 64

// ---------------- dual GEMM: Yl = X@Wl + bl, Yr = X@Wr + br ----------------
#define GR 32
__global__ __launch_bounds__(128) void dual_gemm(
    const float* __restrict__ X,
    const float* __restrict__ Wl, const float* __restrict__ bl,
    const float* __restrict__ Wr, const float* __restrict__ br,
    float* __restrict__ Yl, float* __restrict__ Yr, int nrows)
{
  __shared__ float Xs[GR][F];
  const int row0 = blockIdx.x * GR;
  const int t = threadIdx.x;  // 0..127, also the output column
  #pragma unroll
  for (int i = 0; i < GR; ++i) {
    int r = row0 + i;
    Xs[i][t] = (r < nrows) ? X[(size_t)r * F + t] : 0.0f;
  }
  __syncthreads();
  const int c = t;
  float accl[GR], accr[GR];
  const float bl0 = bl[c], br0 = br[c];
  #pragma unroll
  for (int r = 0; r < GR; ++r) { accl[r] = bl0; accr[r] = br0; }
  for (int k4 = 0; k4 < F / 4; ++k4) {
    float wl[4], wr[4];
    #pragma unroll
    for (int j = 0; j < 4; ++j) {
      wl[j] = Wl[(k4 * 4 + j) * F + c];
      wr[j] = Wr[(k4 * 4 + j) * F + c];
    }
    #pragma unroll
    for (int r = 0; r < GR; ++r) {
      float4 xv = *reinterpret_cast<const float4*>(&Xs[r][k4 * 4]);
      accl[r] = fmaf(xv.x, wl[0], accl[r]);
      accl[r] = fmaf(xv.y, wl[1], accl[r]);
      accl[r] = fmaf(xv.z, wl[2], accl[r]);
      accl[r] = fmaf(xv.w, wl[3], accl[r]);
      accr[r] = fmaf(xv.x, wr[0], accr[r]);
      accr[r] = fmaf(xv.y, wr[1], accr[r]);
      accr[r] = fmaf(xv.z, wr[2], accr[r]);
      accr[r] = fmaf(xv.w, wr[3], accr[r]);
    }
  }
  #pragma unroll
  for (int r = 0; r < GR; ++r) {
    int rr = row0 + r;
    if (rr < nrows) {
      Yl[(size_t)rr * F + c] = accl[r];
      Yr[(size_t)rr * F + c] = accr[r];
    }
  }
}

// ---------------- CSR build ----------------
__global__ void k_count(const int* __restrict__ dst, int* __restrict__ cnt, int E_) {
  int e = blockIdx.x * blockDim.x + threadIdx.x;
  if (e < E_) atomicAdd(&cnt[dst[e]], 1);
}

__global__ __launch_bounds__(256) void k_scan1(const int* __restrict__ in,
                                               int* __restrict__ out,
                                               int* __restrict__ bsum, int n) {
  __shared__ int lds[256];
  int b = blockIdx.x, t = threadIdx.x;
  int base = b * 1024 + t * 4;
  int v[4]; int s = 0;
  #pragma unroll
  for (int j = 0; j < 4; ++j) { v[j] = (base + j < n) ? in[base + j] : 0; s += v[j]; }
  lds[t] = s;
  __syncthreads();
  for (int d = 1; d < 256; d <<= 1) {
    int x = (t >= d) ? lds[t - d] : 0;
    __syncthreads();
    lds[t] += x;
    __syncthreads();
  }
  int incl = lds[t];
  int excl = incl - s;
  if (t == 255) bsum[b] = incl;
  int run = excl;
  #pragma unroll
  for (int j = 0; j < 4; ++j) {
    if (base + j < n) out[base + j] = run;
    run += v[j];
  }
}

__global__ void k_scan2(int* bsum, int nb) {
  if (threadIdx.x == 0 && blockIdx.x == 0) {
    int run = 0;
    for (int i = 0; i < nb; ++i) { int v = bsum[i]; bsum[i] = run; run += v; }
  }
}

__global__ void k_scan3(int* __restrict__ rowptr, const int* __restrict__ bsum,
                        int n, int total) {
  int i = blockIdx.x * blockDim.x + threadIdx.x;
  if (i < n) rowptr[i] += bsum[i >> 10];
  if (i == 0) rowptr[n] = total;
}

__global__ void k_fill(const int* __restrict__ src, const int* __restrict__ dst,
                       int* __restrict__ cursor, int* __restrict__ srclist,
                       int* __restrict__ dstlist, int E_) {
  int e = blockIdx.x * blockDim.x + threadIdx.x;
  if (e < E_) {
    int d = dst[e];
    int pos = atomicAdd(&cursor[d], 1);
    srclist[pos] = src[e];
    dstlist[pos] = d;
  }
}

// ---------------- edge-parallel scores, conv1 (8 heads) -------------------
__global__ __launch_bounds__(256) void score1(
    const float* __restrict__ xl, const float* __restrict__ xr,
    const int* __restrict__ srclist, const int* __restrict__ dstlist,
    const float* __restrict__ att, float* __restrict__ p1, int E_, int S_)
{
  int wid = (blockIdx.x * blockDim.x + threadIdx.x) >> 6;
  int lane = threadIdx.x & 63;
  int slot = wid * 2 + (lane >> 5);
  if (slot >= S_) return;
  int l = lane & 31;
  int src, dstn;
  if (slot < E_) { src = srclist[slot]; dstn = dstlist[slot]; }
  else { src = slot - E_; dstn = src; }
  int c0 = l * 4;
  float4 xlv = *reinterpret_cast<const float4*>(&xl[(size_t)src * F + c0]);
  float4 xrv = *reinterpret_cast<const float4*>(&xr[(size_t)dstn * F + c0]);
  float4 av  = *reinterpret_cast<const float4*>(&att[c0]);
  float t, s = 0.0f;
  t = xlv.x + xrv.x; t = t > 0.f ? t : 0.2f * t; s = fmaf(t, av.x, s);
  t = xlv.y + xrv.y; t = t > 0.f ? t : 0.2f * t; s = fmaf(t, av.y, s);
  t = xlv.z + xrv.z; t = t > 0.f ? t : 0.2f * t; s = fmaf(t, av.z, s);
  t = xlv.w + xrv.w; t = t > 0.f ? t : 0.2f * t; s = fmaf(t, av.w, s);
  s += __shfl_xor(s, 1);
  s += __shfl_xor(s, 2);
  if ((l & 3) == 0) p1[(size_t)slot * 8 + (l >> 2)] = __expf(s);
}

// ---------------- edge-parallel scores, conv2 (1 head, 128 ch) ------------
__global__ __launch_bounds__(256) void score2(
    const float* __restrict__ xl, const float* __restrict__ xr,
    const int* __restrict__ srclist, const int* __restrict__ dstlist,
    const float* __restrict__ att, float* __restrict__ p2, int E_, int S_)
{
  int wid = (blockIdx.x * blockDim.x + threadIdx.x) >> 6;
  int lane = threadIdx.x & 63;
  int slot = wid * 2 + (lane >> 5);
  if (slot >= S_) return;
  int l = lane & 31;
  int src, dstn;
  if (slot < E_) { src = srclist[slot]; dstn = dstlist[slot]; }
  else { src = slot - E_; dstn = src; }
  int c0 = l * 4;
  float4 xlv = *reinterpret_cast<const float4*>(&xl[(size_t)src * F + c0]);
  float4 xrv = *reinterpret_cast<const float4*>(&xr[(size_t)dstn * F + c0]);
  float4 av  = *reinterpret_cast<const float4*>(&att[c0]);
  float t, s = 0.0f;
  t = xlv.x + xrv.x; t = t > 0.f ? t : 0.2f * t; s = fmaf(t, av.x, s);
  t = xlv.y + xrv.y; t = t > 0.f ? t : 0.2f * t; s = fmaf(t, av.y, s);
  t = xlv.z + xrv.z; t = t > 0.f ? t : 0.2f * t; s = fmaf(t, av.z, s);
  t = xlv.w + xrv.w; t = t > 0.f ? t : 0.2f * t; s = fmaf(t, av.w, s);
  s += __shfl_xor(s, 1);
  s += __shfl_xor(s, 2);
  s += __shfl_xor(s, 4);
  s += __shfl_xor(s, 8);
  s += __shfl_xor(s, 16);
  if (l == 0) p2[slot] = __expf(s);
}

// ---------------- node aggregation conv1 (shuffle-free) + ELU -------------
__global__ __launch_bounds__(256) void node_agg1(
    const float* __restrict__ xl, const int* __restrict__ rowptr,
    const int* __restrict__ srclist, const float* __restrict__ p1,
    const float* __restrict__ bias, float* __restrict__ out, int Nn, int E_)
{
  int wid = (blockIdx.x * blockDim.x + threadIdx.x) >> 6;
  int lane = threadIdx.x & 63;
  if (wid >= Nn) return;
  const int n = wid;
  const int c0 = lane * 2;
  const int h = lane >> 3;
  float2 xls = *reinterpret_cast<const float2*>(&xl[(size_t)n * F + c0]);
  float pv = p1[((size_t)(E_ + n)) * 8 + h];   // self-loop
  float den = pv, a0 = pv * xls.x, a1 = pv * xls.y;
  const int beg = rowptr[n], end = rowptr[n + 1];
  #pragma unroll 2
  for (int i = beg; i < end; ++i) {
    int s = srclist[i];
    float pe = p1[(size_t)i * 8 + h];
    float2 xv = *reinterpret_cast<const float2*>(&xl[(size_t)s * F + c0]);
    den += pe;
    a0 = fmaf(pe, xv.x, a0);
    a1 = fmaf(pe, xv.y, a1);
  }
  float inv = 1.0f / den;
  float o0 = a0 * inv + bias[c0];
  float o1 = a1 * inv + bias[c0 + 1];
  o0 = o0 > 0.f ? o0 : (__expf(o0) - 1.0f);
  o1 = o1 > 0.f ? o1 : (__expf(o1) - 1.0f);
  *reinterpret_cast<float2*>(&out[(size_t)n * F + c0]) = make_float2(o0, o1);
}

// ---------------- node aggregation conv2 (shuffle-free) + ELU -------------
__global__ __launch_bounds__(256) void node_agg2(
    const float* __restrict__ xl, const int* __restrict__ rowptr,
    const int* __restrict__ srclist, const float* __restrict__ p2,
    const float* __restrict__ bias, float* __restrict__ out, int Nn, int E_)
{
  int wid = (blockIdx.x * blockDim.x + threadIdx.x) >> 6;
  int lane = threadIdx.x & 63;
  if (wid >= Nn) return;
  const int n = wid;
  const int c0 = lane * 2;
  float2 xls = *reinterpret_cast<const float2*>(&xl[(size_t)n * F + c0]);
  float pv = p2[E_ + n];                       // self-loop
  float den = pv, a0 = pv * xls.x, a1 = pv * xls.y;
  const int beg = rowptr[n], end = rowptr[n + 1];
  #pragma unroll 2
  for (int i = beg; i < end; ++i) {
    int s = srclist[i];
    float pe = p2[i];
    float2 xv = *reinterpret_cast<const float2*>(&xl[(size_t)s * F + c0]);
    den += pe;
    a0 = fmaf(pe, xv.x, a0);
    a1 = fmaf(pe, xv.y, a1);
  }
  float inv = 1.0f / den;
  float o0 = a0 * inv + bias[c0];
  float o1 = a1 * inv + bias[c0 + 1];
  o0 = o0 > 0.f ? o0 : (__expf(o0) - 1.0f);
  o1 = o1 > 0.f ? o1 : (__expf(o1) - 1.0f);
  *reinterpret_cast<float2*>(&out[(size_t)n * F + c0]) = make_float2(o0, o1);
}

// ---------------- chunked mean pool stage 1 (batch sorted) ----------------
#define PB 128  // nodes per block
__global__ __launch_bounds__(128) void k_pool1(
    const float* __restrict__ h2, const int* __restrict__ batch,
    float* __restrict__ sums, int Nn)
{
  int c = threadIdx.x;             // channel
  int n0 = blockIdx.x * PB;
  if (n0 >= Nn) return;
  int n1 = n0 + PB; if (n1 > Nn) n1 = Nn;
  int gcur = batch[n0];
  float acc = 0.f;
  for (int n = n0; n < n1; ++n) {
    int g = batch[n];
    if (g != gcur) { atomicAdd(&sums[gcur * F + c], acc); acc = 0.f; gcur = g; }
    acc += h2[(size_t)n * F + c];
  }
  atomicAdd(&sums[gcur * F + c], acc);
}

// ---------------- per-graph counts (batch sorted; binary search) ----------
__global__ void k_counts(const int* __restrict__ batch, float* __restrict__ gcnt, int Nn) {
  int g = threadIdx.x;
  if (g >= NG) return;
  int lo = 0, hi = Nn;
  while (lo < hi) { int mid = (lo + hi) >> 1; if (batch[mid] < g) lo = mid + 1; else hi = mid; }
  int lo2 = lo, hi2 = Nn;
  while (lo2 < hi2) { int mid = (lo2 + hi2) >> 1; if (batch[mid] < g + 1) lo2 = mid + 1; else hi2 = mid; }
  int cnt = lo2 - lo;
  gcnt[g] = (float)(cnt > 1 ? cnt : 1);
}

// ---------------- final: out = (sums/cnt) @ W3 + b3 ----------------
__global__ void k_final(const float* __restrict__ sums, const float* __restrict__ gcnt,
                        const float* __restrict__ W3, const float* __restrict__ b3,
                        float* __restrict__ out)
{
  int t = blockIdx.x * blockDim.x + threadIdx.x;
  if (t >= NG * NCLS) return;
  int g = t / NCLS, k = t % NCLS;
  float acc = 0.f;
  for (int cc = 0; cc < F; ++cc) acc = fmaf(sums[g * F + cc], W3[cc * NCLS + k], acc);
  out[t] = acc / gcnt[g] + b3[k];
}

extern "C" void kernel_launch(void* const* d_in, const int* in_sizes, int n_in,
                              void* d_out, int out_size, void* d_ws, size_t ws_size,
                              hipStream_t stream)
{
  const float* x     = (const float*)d_in[0];
  const int*   ei    = (const int*)d_in[1];
  const int*   batch = (const int*)d_in[2];
  const float* W1l = (const float*)d_in[3];
  const float* b1l = (const float*)d_in[4];
  const float* W1r = (const float*)d_in[5];
  const float* b1r = (const float*)d_in[6];
  const float* att1  = (const float*)d_in[7];
  const float* bias1 = (const float*)d_in[8];
  const float* W2l = (const float*)d_in[9];
  const float* b2l = (const float*)d_in[10];
  const float* W2r = (const float*)d_in[11];
  const float* b2r = (const float*)d_in[12];
  const float* att2  = (const float*)d_in[13];
  const float* bias2 = (const float*)d_in[14];
  const float* W3 = (const float*)d_in[15];
  const float* b3 = (const float*)d_in[16];

  const int Nn = in_sizes[0] / F;
  const int Ee = in_sizes[1] / 2;
  const int Ss = Ee + Nn;   // edge slots + self-loop slots
  const int* srcp = ei;
  const int* dstp = ei + Ee;

  char* ws = (char*)d_ws;
  size_t off = 0;
  auto alloc = [&](size_t bytes) -> void* {
    void* p = ws + off;
    off = (off + bytes + 255) & ~size_t(255);
    return p;
  };
  float* xl      = (float*)alloc((size_t)Nn * F * 4);
  float* xr      = (float*)alloc((size_t)Nn * F * 4);
  float* h12     = (float*)alloc((size_t)Nn * F * 4);   // h1, then reused as h2
  float* p12     = (float*)alloc((size_t)Ss * 8 * 4);   // p1 [S][8]; p2 uses first S
  int*   cnt     = (int*)alloc((size_t)Nn * 4);         // count, later cursor
  int*   rowptr  = (int*)alloc((size_t)(Nn + 1) * 4);
  int*   srclist = (int*)alloc((size_t)Ee * 4);
  int*   dstlist = (int*)alloc((size_t)Ee * 4);
  float* sums    = (float*)alloc((size_t)(NG * F + NG) * 4);  // sums + gcnt
  float* gcnt    = sums + NG * F;
  int*   bsum    = (int*)alloc(1024);

  hipMemsetAsync(cnt, 0, (size_t)Nn * 4, stream);
  hipMemsetAsync(sums, 0, (size_t)NG * F * 4, stream);

  const int TB = 256;
  // CSR build
  k_count<<<(Ee + TB - 1) / TB, TB, 0, stream>>>(dstp, cnt, Ee);
  int nb = (Nn + 1023) / 1024;
  k_scan1<<<nb, 256, 0, stream>>>(cnt, rowptr, bsum, Nn);
  k_scan2<<<1, 64, 0, stream>>>(bsum, nb);
  k_scan3<<<(Nn + TB - 1) / TB, TB, 0, stream>>>(rowptr, bsum, Nn, Ee);
  hipMemcpyAsync(cnt, rowptr, (size_t)Nn * 4, hipMemcpyDeviceToDevice, stream);
  k_fill<<<(Ee + TB - 1) / TB, TB, 0, stream>>>(srcp, dstp, cnt, srclist, dstlist, Ee);

  int score_blocks = ((Ss + 1) / 2 + 3) / 4;   // 2 slots/wave, 4 waves/block
  int node_blocks  = (Nn + 3) / 4;

  // conv1
  dual_gemm<<<(Nn + GR - 1) / GR, 128, 0, stream>>>(x, W1l, b1l, W1r, b1r, xl, xr, Nn);
  score1<<<score_blocks, 256, 0, stream>>>(xl, xr, srclist, dstlist, att1, p12, Ee, Ss);
  node_agg1<<<node_blocks, 256, 0, stream>>>(xl, rowptr, srclist, p12, bias1, h12, Nn, Ee);
  // conv2
  dual_gemm<<<(Nn + GR - 1) / GR, 128, 0, stream>>>(h12, W2l, b2l, W2r, b2r, xl, xr, Nn);
  score2<<<score_blocks, 256, 0, stream>>>(xl, xr, srclist, dstlist, att2, p12, Ee, Ss);
  node_agg2<<<node_blocks, 256, 0, stream>>>(xl, rowptr, srclist, p12, bias2, h12, Nn, Ee);
  // pool + head
  k_pool1<<<(Nn + PB - 1) / PB, 128, 0, stream>>>(h12, batch, sums, Nn);
  k_counts<<<1, 64, 0, stream>>>(batch, gcnt, Nn);
  k_final<<<(NG * NCLS + 255) / 256, 256, 0, stream>>>(sums, gcnt, W3, b3, (float*)d_out);
}

// Round 7
// 1114.094 us; speedup vs baseline: 1.6411x; 1.0892x over previous
//
#include <hip/hip_runtime.h>

#define F 128
#define NCLS 10
#define NG 64

// bf16 helpers (RTN store, exact load)
__device__ __forceinline__ unsigned short f2bf(float f) {
  unsigned int u = __float_as_uint(f);
  u += 0x7FFFu + ((u >> 16) & 1u);
  return (unsigned short)(u >> 16);
}
__device__ __forceinline__ float bflo(unsigned int u) {   // low 16 bits
  return __uint_as_float(u << 16);
}
__device__ __forceinline__ float bfhi(unsigned int u) {   // high 16 bits
  return __uint_as_float(u & 0xFFFF0000u);
}

// ---------------- dual GEMM: Yl = bf16(X@Wl+bl), Yr = bf16(X@Wr+br) -------
#define GR 32
__global__ __launch_bounds__(128) void dual_gemm(
    const float* __restrict__ X,
    const float* __restrict__ Wl, const float* __restrict__ bl,
    const float* __restrict__ Wr, const float* __restrict__ br,
    unsigned short* __restrict__ Yl, unsigned short* __restrict__ Yr, int nrows)
{
  __shared__ float Xs[GR][F];
  const int row0 = blockIdx.x * GR;
  const int t = threadIdx.x;  // 0..127, also the output column
  #pragma unroll
  for (int i = 0; i < GR; ++i) {
    int r = row0 + i;
    Xs[i][t] = (r < nrows) ? X[(size_t)r * F + t] : 0.0f;
  }
  __syncthreads();
  const int c = t;
  float accl[GR], accr[GR];
  const float bl0 = bl[c], br0 = br[c];
  #pragma unroll
  for (int r = 0; r < GR; ++r) { accl[r] = bl0; accr[r] = br0; }
  for (int k4 = 0; k4 < F / 4; ++k4) {
    float wl[4], wr[4];
    #pragma unroll
    for (int j = 0; j < 4; ++j) {
      wl[j] = Wl[(k4 * 4 + j) * F + c];
      wr[j] = Wr[(k4 * 4 + j) * F + c];
    }
    #pragma unroll
    for (int r = 0; r < GR; ++r) {
      float4 xv = *reinterpret_cast<const float4*>(&Xs[r][k4 * 4]);
      accl[r] = fmaf(xv.x, wl[0], accl[r]);
      accl[r] = fmaf(xv.y, wl[1], accl[r]);
      accl[r] = fmaf(xv.z, wl[2], accl[r]);
      accl[r] = fmaf(xv.w, wl[3], accl[r]);
      accr[r] = fmaf(xv.x, wr[0], accr[r]);
      accr[r] = fmaf(xv.y, wr[1], accr[r]);
      accr[r] = fmaf(xv.z, wr[2], accr[r]);
      accr[r] = fmaf(xv.w, wr[3], accr[r]);
    }
  }
  #pragma unroll
  for (int r = 0; r < GR; ++r) {
    int rr = row0 + r;
    if (rr < nrows) {
      Yl[(size_t)rr * F + c] = f2bf(accl[r]);
      Yr[(size_t)rr * F + c] = f2bf(accr[r]);
    }
  }
}

// ---------------- CSR build ----------------
__global__ void k_count(const int* __restrict__ dst, int* __restrict__ cnt, int E_) {
  int e = blockIdx.x * blockDim.x + threadIdx.x;
  if (e < E_) atomicAdd(&cnt[dst[e]], 1);
}

__global__ __launch_bounds__(256) void k_scan1(const int* __restrict__ in,
                                               int* __restrict__ out,
                                               int* __restrict__ bsum, int n) {
  __shared__ int lds[256];
  int b = blockIdx.x, t = threadIdx.x;
  int base = b * 1024 + t * 4;
  int v[4]; int s = 0;
  #pragma unroll
  for (int j = 0; j < 4; ++j) { v[j] = (base + j < n) ? in[base + j] : 0; s += v[j]; }
  lds[t] = s;
  __syncthreads();
  for (int d = 1; d < 256; d <<= 1) {
    int x = (t >= d) ? lds[t - d] : 0;
    __syncthreads();
    lds[t] += x;
    __syncthreads();
  }
  int incl = lds[t];
  int excl = incl - s;
  if (t == 255) bsum[b] = incl;
  int run = excl;
  #pragma unroll
  for (int j = 0; j < 4; ++j) {
    if (base + j < n) out[base + j] = run;
    run += v[j];
  }
}

__global__ void k_scan2(int* bsum, int nb) {
  if (threadIdx.x == 0 && blockIdx.x == 0) {
    int run = 0;
    for (int i = 0; i < nb; ++i) { int v = bsum[i]; bsum[i] = run; run += v; }
  }
}

__global__ void k_scan3(int* __restrict__ rowptr, const int* __restrict__ bsum,
                        int n, int total) {
  int i = blockIdx.x * blockDim.x + threadIdx.x;
  if (i < n) rowptr[i] += bsum[i >> 10];
  if (i == 0) rowptr[n] = total;
}

__global__ void k_fill(const int* __restrict__ src, const int* __restrict__ dst,
                       int* __restrict__ cursor, int* __restrict__ srclist,
                       int* __restrict__ dstlist, int E_) {
  int e = blockIdx.x * blockDim.x + threadIdx.x;
  if (e < E_) {
    int d = dst[e];
    int pos = atomicAdd(&cursor[d], 1);
    srclist[pos] = src[e];
    dstlist[pos] = d;
  }
}

// ---------------- edge-parallel scores, conv1 (8 heads) -------------------
// 32 lanes per slot, 4 channels per lane (uint2 = 4 bf16).
__global__ __launch_bounds__(256) void score1(
    const unsigned short* __restrict__ xl, const unsigned short* __restrict__ xr,
    const int* __restrict__ srclist, const int* __restrict__ dstlist,
    const float* __restrict__ att, float* __restrict__ p1, int E_, int S_)
{
  int wid = (blockIdx.x * blockDim.x + threadIdx.x) >> 6;
  int lane = threadIdx.x & 63;
  int slot = wid * 2 + (lane >> 5);
  if (slot >= S_) return;
  int l = lane & 31;
  int src, dstn;
  if (slot < E_) { src = srclist[slot]; dstn = dstlist[slot]; }
  else { src = slot - E_; dstn = src; }
  int c0 = l * 4;
  uint2 ua = *reinterpret_cast<const uint2*>(&xl[(size_t)src * F + c0]);
  uint2 ub = *reinterpret_cast<const uint2*>(&xr[(size_t)dstn * F + c0]);
  float4 av = *reinterpret_cast<const float4*>(&att[c0]);
  float t, s = 0.0f;
  t = bflo(ua.x) + bflo(ub.x); t = t > 0.f ? t : 0.2f * t; s = fmaf(t, av.x, s);
  t = bfhi(ua.x) + bfhi(ub.x); t = t > 0.f ? t : 0.2f * t; s = fmaf(t, av.y, s);
  t = bflo(ua.y) + bflo(ub.y); t = t > 0.f ? t : 0.2f * t; s = fmaf(t, av.z, s);
  t = bfhi(ua.y) + bfhi(ub.y); t = t > 0.f ? t : 0.2f * t; s = fmaf(t, av.w, s);
  s += __shfl_xor(s, 1);
  s += __shfl_xor(s, 2);
  if ((l & 3) == 0) p1[(size_t)slot * 8 + (l >> 2)] = __expf(s);
}

// ---------------- edge-parallel scores, conv2 (1 head, 128 ch) ------------
__global__ __launch_bounds__(256) void score2(
    const unsigned short* __restrict__ xl, const unsigned short* __restrict__ xr,
    const int* __restrict__ srclist, const int* __restrict__ dstlist,
    const float* __restrict__ att, float* __restrict__ p2, int E_, int S_)
{
  int wid = (blockIdx.x * blockDim.x + threadIdx.x) >> 6;
  int lane = threadIdx.x & 63;
  int slot = wid * 2 + (lane >> 5);
  if (slot >= S_) return;
  int l = lane & 31;
  int src, dstn;
  if (slot < E_) { src = srclist[slot]; dstn = dstlist[slot]; }
  else { src = slot - E_; dstn = src; }
  int c0 = l * 4;
  uint2 ua = *reinterpret_cast<const uint2*>(&xl[(size_t)src * F + c0]);
  uint2 ub = *reinterpret_cast<const uint2*>(&xr[(size_t)dstn * F + c0]);
  float4 av = *reinterpret_cast<const float4*>(&att[c0]);
  float t, s = 0.0f;
  t = bflo(ua.x) + bflo(ub.x); t = t > 0.f ? t : 0.2f * t; s = fmaf(t, av.x, s);
  t = bfhi(ua.x) + bfhi(ub.x); t = t > 0.f ? t : 0.2f * t; s = fmaf(t, av.y, s);
  t = bflo(ua.y) + bflo(ub.y); t = t > 0.f ? t : 0.2f * t; s = fmaf(t, av.z, s);
  t = bfhi(ua.y) + bfhi(ub.y); t = t > 0.f ? t : 0.2f * t; s = fmaf(t, av.w, s);
  s += __shfl_xor(s, 1);
  s += __shfl_xor(s, 2);
  s += __shfl_xor(s, 4);
  s += __shfl_xor(s, 8);
  s += __shfl_xor(s, 16);
  if (l == 0) p2[slot] = __expf(s);
}

// ---------------- node aggregation conv1 (shuffle-free) + ELU -------------
__global__ __launch_bounds__(256) void node_agg1(
    const unsigned short* __restrict__ xl, const int* __restrict__ rowptr,
    const int* __restrict__ srclist, const float* __restrict__ p1,
    const float* __restrict__ bias, float* __restrict__ out, int Nn, int E_)
{
  int wid = (blockIdx.x * blockDim.x + threadIdx.x) >> 6;
  int lane = threadIdx.x & 63;
  if (wid >= Nn) return;
  const int n = wid;
  const int c0 = lane * 2;
  const int h = lane >> 3;
  unsigned int us = *reinterpret_cast<const unsigned int*>(&xl[(size_t)n * F + c0]);
  float xs0 = bflo(us), xs1 = bfhi(us);
  float pv = p1[((size_t)(E_ + n)) * 8 + h];   // self-loop
  float den = pv, a0 = pv * xs0, a1 = pv * xs1;
  const int beg = rowptr[n], end = rowptr[n + 1];
  #pragma unroll 2
  for (int i = beg; i < end; ++i) {
    int s = srclist[i];
    float pe = p1[(size_t)i * 8 + h];
    unsigned int uv = *reinterpret_cast<const unsigned int*>(&xl[(size_t)s * F + c0]);
    den += pe;
    a0 = fmaf(pe, bflo(uv), a0);
    a1 = fmaf(pe, bfhi(uv), a1);
  }
  float inv = 1.0f / den;
  float o0 = a0 * inv + bias[c0];
  float o1 = a1 * inv + bias[c0 + 1];
  o0 = o0 > 0.f ? o0 : (__expf(o0) - 1.0f);
  o1 = o1 > 0.f ? o1 : (__expf(o1) - 1.0f);
  *reinterpret_cast<float2*>(&out[(size_t)n * F + c0]) = make_float2(o0, o1);
}

// ---------------- node aggregation conv2 (shuffle-free) + ELU -------------
__global__ __launch_bounds__(256) void node_agg2(
    const unsigned short* __restrict__ xl, const int* __restrict__ rowptr,
    const int* __restrict__ srclist, const float* __restrict__ p2,
    const float* __restrict__ bias, float* __restrict__ out, int Nn, int E_)
{
  int wid = (blockIdx.x * blockDim.x + threadIdx.x) >> 6;
  int lane = threadIdx.x & 63;
  if (wid >= Nn) return;
  const int n = wid;
  const int c0 = lane * 2;
  unsigned int us = *reinterpret_cast<const unsigned int*>(&xl[(size_t)n * F + c0]);
  float xs0 = bflo(us), xs1 = bfhi(us);
  float pv = p2[E_ + n];                       // self-loop
  float den = pv, a0 = pv * xs0, a1 = pv * xs1;
  const int beg = rowptr[n], end = rowptr[n + 1];
  #pragma unroll 2
  for (int i = beg; i < end; ++i) {
    int s = srclist[i];
    float pe = p2[i];
    unsigned int uv = *reinterpret_cast<const unsigned int*>(&xl[(size_t)s * F + c0]);
    den += pe;
    a0 = fmaf(pe, bflo(uv), a0);
    a1 = fmaf(pe, bfhi(uv), a1);
  }
  float inv = 1.0f / den;
  float o0 = a0 * inv + bias[c0];
  float o1 = a1 * inv + bias[c0 + 1];
  o0 = o0 > 0.f ? o0 : (__expf(o0) - 1.0f);
  o1 = o1 > 0.f ? o1 : (__expf(o1) - 1.0f);
  *reinterpret_cast<float2*>(&out[(size_t)n * F + c0]) = make_float2(o0, o1);
}

// ---------------- chunked mean pool stage 1 (batch sorted) ----------------
#define PB 128  // nodes per block
__global__ __launch_bounds__(128) void k_pool1(
    const float* __restrict__ h2, const int* __restrict__ batch,
    float* __restrict__ sums, int Nn)
{
  int c = threadIdx.x;             // channel
  int n0 = blockIdx.x * PB;
  if (n0 >= Nn) return;
  int n1 = n0 + PB; if (n1 > Nn) n1 = Nn;
  int gcur = batch[n0];
  float acc = 0.f;
  for (int n = n0; n < n1; ++n) {
    int g = batch[n];
    if (g != gcur) { atomicAdd(&sums[gcur * F + c], acc); acc = 0.f; gcur = g; }
    acc += h2[(size_t)n * F + c];
  }
  atomicAdd(&sums[gcur * F + c], acc);
}

// ---------------- per-graph counts (batch sorted; binary search) ----------
__global__ void k_counts(const int* __restrict__ batch, float* __restrict__ gcnt, int Nn) {
  int g = threadIdx.x;
  if (g >= NG) return;
  int lo = 0, hi = Nn;
  while (lo < hi) { int mid = (lo + hi) >> 1; if (batch[mid] < g) lo = mid + 1; else hi = mid; }
  int lo2 = lo, hi2 = Nn;
  while (lo2 < hi2) { int mid = (lo2 + hi2) >> 1; if (batch[mid] < g + 1) lo2 = mid + 1; else hi2 = mid; }
  int cnt = lo2 - lo;
  gcnt[g] = (float)(cnt > 1 ? cnt : 1);
}

// ---------------- final: out = (sums/cnt) @ W3 + b3 ----------------
__global__ void k_final(const float* __restrict__ sums, const float* __restrict__ gcnt,
                        const float* __restrict__ W3, const float* __restrict__ b3,
                        float* __restrict__ out)
{
  int t = blockIdx.x * blockDim.x + threadIdx.x;
  if (t >= NG * NCLS) return;
  int g = t / NCLS, k = t % NCLS;
  float acc = 0.f;
  for (int cc = 0; cc < F; ++cc) acc = fmaf(sums[g * F + cc], W3[cc * NCLS + k], acc);
  out[t] = acc / gcnt[g] + b3[k];
}

extern "C" void kernel_launch(void* const* d_in, const int* in_sizes, int n_in,
                              void* d_out, int out_size, void* d_ws, size_t ws_size,
                              hipStream_t stream)
{
  const float* x     = (const float*)d_in[0];
  const int*   ei    = (const int*)d_in[1];
  const int*   batch = (const int*)d_in[2];
  const float* W1l = (const float*)d_in[3];
  const float* b1l = (const float*)d_in[4];
  const float* W1r = (const float*)d_in[5];
  const float* b1r = (const float*)d_in[6];
  const float* att1  = (const float*)d_in[7];
  const float* bias1 = (const float*)d_in[8];
  const float* W2l = (const float*)d_in[9];
  const float* b2l = (const float*)d_in[10];
  const float* W2r = (const float*)d_in[11];
  const float* b2r = (const float*)d_in[12];
  const float* att2  = (const float*)d_in[13];
  const float* bias2 = (const float*)d_in[14];
  const float* W3 = (const float*)d_in[15];
  const float* b3 = (const float*)d_in[16];

  const int Nn = in_sizes[0] / F;
  const int Ee = in_sizes[1] / 2;
  const int Ss = Ee + Nn;   // edge slots + self-loop slots
  const int* srcp = ei;
  const int* dstp = ei + Ee;

  char* ws = (char*)d_ws;
  size_t off = 0;
  auto alloc = [&](size_t bytes) -> void* {
    void* p = ws + off;
    off = (off + bytes + 255) & ~size_t(255);
    return p;
  };
  unsigned short* xl = (unsigned short*)alloc((size_t)Nn * F * 2);
  unsigned short* xr = (unsigned short*)alloc((size_t)Nn * F * 2);
  float* h12     = (float*)alloc((size_t)Nn * F * 4);   // h1, then reused as h2
  float* p12     = (float*)alloc((size_t)Ss * 8 * 4);   // p1 [S][8]; p2 uses first S
  int*   cnt     = (int*)alloc((size_t)Nn * 4);         // count, later cursor
  int*   rowptr  = (int*)alloc((size_t)(Nn + 1) * 4);
  int*   srclist = (int*)alloc((size_t)Ee * 4);
  int*   dstlist = (int*)alloc((size_t)Ee * 4);
  float* sums    = (float*)alloc((size_t)(NG * F + NG) * 4);  // sums + gcnt
  float* gcnt    = sums + NG * F;
  int*   bsum    = (int*)alloc(1024);

  hipMemsetAsync(cnt, 0, (size_t)Nn * 4, stream);
  hipMemsetAsync(sums, 0, (size_t)NG * F * 4, stream);

  const int TB = 256;
  // CSR build
  k_count<<<(Ee + TB - 1) / TB, TB, 0, stream>>>(dstp, cnt, Ee);
  int nb = (Nn + 1023) / 1024;
  k_scan1<<<nb, 256, 0, stream>>>(cnt, rowptr, bsum, Nn);
  k_scan2<<<1, 64, 0, stream>>>(bsum, nb);
  k_scan3<<<(Nn + TB - 1) / TB, TB, 0, stream>>>(rowptr, bsum, Nn, Ee);
  hipMemcpyAsync(cnt, rowptr, (size_t)Nn * 4, hipMemcpyDeviceToDevice, stream);
  k_fill<<<(Ee + TB - 1) / TB, TB, 0, stream>>>(srcp, dstp, cnt, srclist, dstlist, Ee);

  int score_blocks = ((Ss + 1) / 2 + 3) / 4;   // 2 slots/wave, 4 waves/block
  int node_blocks  = (Nn + 3) / 4;

  // conv1
  dual_gemm<<<(Nn + GR - 1) / GR, 128, 0, stream>>>(x, W1l, b1l, W1r, b1r, xl, xr, Nn);
  score1<<<score_blocks, 256, 0, stream>>>(xl, xr, srclist, dstlist, att1, p12, Ee, Ss);
  node_agg1<<<node_blocks, 256, 0, stream>>>(xl, rowptr, srclist, p12, bias1, h12, Nn, Ee);
  // conv2
  dual_gemm<<<(Nn + GR - 1) / GR, 128, 0, stream>>>(h12, W2l, b2l, W2r, b2r, xl, xr, Nn);
  score2<<<score_blocks, 256, 0, stream>>>(xl, xr, srclist, dstlist, att2, p12, Ee, Ss);
  node_agg2<<<node_blocks, 256, 0, stream>>>(xl, rowptr, srclist, p12, bias2, h12, Nn, Ee);
  // pool + head
  k_pool1<<<(Nn + PB - 1) / PB, 128, 0, stream>>>(h12, batch, sums, Nn);
  k_counts<<<1, 64, 0, stream>>>(batch, gcnt, Nn);
  k_final<<<(NG * NCLS + 255) / 256, 256, 0, stream>>>(sums, gcnt, W3, b3, (float*)d_out);
}

// Round 13
// 939.211 us; speedup vs baseline: 1.9467x; 1.1862x over previous
//
#include <hip/hip_runtime.h>

#define F 128
#define NCLS 10
#define NG 64

// bf16 helpers (RTN store, exact load)
__device__ __forceinline__ unsigned short f2bf(float f) {
  unsigned int u = __float_as_uint(f);
  u += 0x7FFFu + ((u >> 16) & 1u);
  return (unsigned short)(u >> 16);
}
__device__ __forceinline__ float bflo(unsigned int u) {   // low 16 bits
  return __uint_as_float(u << 16);
}
__device__ __forceinline__ float bfhi(unsigned int u) {   // high 16 bits
  return __uint_as_float(u & 0xFFFF0000u);
}

// ---------------- dual GEMM: Yl = bf16(X@Wl+bl), Yr = bf16(X@Wr+br) -------
#define GR 32
__global__ __launch_bounds__(128) void dual_gemm(
    const float* __restrict__ X,
    const float* __restrict__ Wl, const float* __restrict__ bl,
    const float* __restrict__ Wr, const float* __restrict__ br,
    unsigned short* __restrict__ Yl, unsigned short* __restrict__ Yr, int nrows)
{
  __shared__ float Xs[GR][F];
  const int row0 = blockIdx.x * GR;
  const int t = threadIdx.x;  // 0..127, also the output column
  #pragma unroll
  for (int i = 0; i < GR; ++i) {
    int r = row0 + i;
    Xs[i][t] = (r < nrows) ? X[(size_t)r * F + t] : 0.0f;
  }
  __syncthreads();
  const int c = t;
  float accl[GR], accr[GR];
  const float bl0 = bl[c], br0 = br[c];
  #pragma unroll
  for (int r = 0; r < GR; ++r) { accl[r] = bl0; accr[r] = br0; }
  for (int k4 = 0; k4 < F / 4; ++k4) {
    float wl[4], wr[4];
    #pragma unroll
    for (int j = 0; j < 4; ++j) {
      wl[j] = Wl[(k4 * 4 + j) * F + c];
      wr[j] = Wr[(k4 * 4 + j) * F + c];
    }
    #pragma unroll
    for (int r = 0; r < GR; ++r) {
      float4 xv = *reinterpret_cast<const float4*>(&Xs[r][k4 * 4]);
      accl[r] = fmaf(xv.x, wl[0], accl[r]);
      accl[r] = fmaf(xv.y, wl[1], accl[r]);
      accl[r] = fmaf(xv.z, wl[2], accl[r]);
      accl[r] = fmaf(xv.w, wl[3], accl[r]);
      accr[r] = fmaf(xv.x, wr[0], accr[r]);
      accr[r] = fmaf(xv.y, wr[1], accr[r]);
      accr[r] = fmaf(xv.z, wr[2], accr[r]);
      accr[r] = fmaf(xv.w, wr[3], accr[r]);
    }
  }
  #pragma unroll
  for (int r = 0; r < GR; ++r) {
    int rr = row0 + r;
    if (rr < nrows) {
      Yl[(size_t)rr * F + c] = f2bf(accl[r]);
      Yr[(size_t)rr * F + c] = f2bf(accr[r]);
    }
  }
}

// ---------------- CSR build ----------------
__global__ void k_count(const int* __restrict__ dst, int* __restrict__ cnt, int E_) {
  int e = blockIdx.x * blockDim.x + threadIdx.x;
  if (e < E_) atomicAdd(&cnt[dst[e]], 1);
}

__global__ __launch_bounds__(256) void k_scan1(const int* __restrict__ in,
                                               int* __restrict__ out,
                                               int* __restrict__ bsum, int n) {
  __shared__ int lds[256];
  int b = blockIdx.x, t = threadIdx.x;
  int base = b * 1024 + t * 4;
  int v[4]; int s = 0;
  #pragma unroll
  for (int j = 0; j < 4; ++j) { v[j] = (base + j < n) ? in[base + j] : 0; s += v[j]; }
  lds[t] = s;
  __syncthreads();
  for (int d = 1; d < 256; d <<= 1) {
    int x = (t >= d) ? lds[t - d] : 0;
    __syncthreads();
    lds[t] += x;
    __syncthreads();
  }
  int incl = lds[t];
  int excl = incl - s;
  if (t == 255) bsum[b] = incl;
  int run = excl;
  #pragma unroll
  for (int j = 0; j < 4; ++j) {
    if (base + j < n) out[base + j] = run;
    run += v[j];
  }
}

__global__ void k_scan2(int* bsum, int nb) {
  if (threadIdx.x == 0 && blockIdx.x == 0) {
    int run = 0;
    for (int i = 0; i < nb; ++i) { int v = bsum[i]; bsum[i] = run; run += v; }
  }
}

__global__ void k_scan3(int* __restrict__ rowptr, const int* __restrict__ bsum,
                        int n, int total) {
  int i = blockIdx.x * blockDim.x + threadIdx.x;
  if (i < n) rowptr[i] += bsum[i >> 10];
  if (i == 0) rowptr[n] = total;
}

__global__ void k_fill(const int* __restrict__ src, const int* __restrict__ dst,
                       int* __restrict__ cursor, int* __restrict__ srclist,
                       int* __restrict__ dstlist, int E_) {
  int e = blockIdx.x * blockDim.x + threadIdx.x;
  if (e < E_) {
    int d = dst[e];
    int pos = atomicAdd(&cursor[d], 1);
    srclist[pos] = src[e];
    dstlist[pos] = d;
  }
}

// 2 channels of leaky-relu dot, accumulating into s
#define CH2(ua, ub, vx, vy) { \
    float t0 = bflo(ua) + bflo(ub); t0 = fmaxf(t0, 0.2f * t0); s = fmaf(t0, vx, s); \
    float t1 = bfhi(ua) + bfhi(ub); t1 = fmaxf(t1, 0.2f * t1); s = fmaf(t1, vy, s); }

// ---------------- edge-parallel scores, conv1 (8 heads) -------------------
// 8 lanes per slot; lane l handles head l (16 channels). No cross-lane reduce.
__global__ __launch_bounds__(256) void score1(
    const unsigned short* __restrict__ xl, const unsigned short* __restrict__ xr,
    const int* __restrict__ srclist, const int* __restrict__ dstlist,
    const float* __restrict__ att, float* __restrict__ p1, int E_, int S_)
{
  int gtid = blockIdx.x * blockDim.x + threadIdx.x;
  int slot = gtid >> 3;
  if (slot >= S_) return;
  int l = gtid & 7;                 // head
  int src, dstn;
  if (slot < E_) { src = srclist[slot]; dstn = dstlist[slot]; }
  else { src = slot - E_; dstn = src; }
  int c0 = l * 16;
  const uint4* pa = reinterpret_cast<const uint4*>(&xl[(size_t)src * F + c0]);
  const uint4* pb = reinterpret_cast<const uint4*>(&xr[(size_t)dstn * F + c0]);
  uint4 a0 = pa[0], a1 = pa[1];
  uint4 b0 = pb[0], b1 = pb[1];
  const float4* pv = reinterpret_cast<const float4*>(&att[c0]);
  float4 v0 = pv[0], v1 = pv[1], v2 = pv[2], v3 = pv[3];
  float s = 0.0f;
  CH2(a0.x, b0.x, v0.x, v0.y) CH2(a0.y, b0.y, v0.z, v0.w)
  CH2(a0.z, b0.z, v1.x, v1.y) CH2(a0.w, b0.w, v1.z, v1.w)
  CH2(a1.x, b1.x, v2.x, v2.y) CH2(a1.y, b1.y, v2.z, v2.w)
  CH2(a1.z, b1.z, v3.x, v3.y) CH2(a1.w, b1.w, v3.z, v3.w)
  p1[(size_t)slot * 8 + l] = __expf(s);
}

// ---------------- edge-parallel scores, conv2 (1 head, 128 ch) ------------
// 8 lanes per slot, 16 ch per lane, 3-stage reduce within the 8-lane group.
__global__ __launch_bounds__(256) void score2(
    const unsigned short* __restrict__ xl, const unsigned short* __restrict__ xr,
    const int* __restrict__ srclist, const int* __restrict__ dstlist,
    const float* __restrict__ att, float* __restrict__ p2, int E_, int S_)
{
  int gtid = blockIdx.x * blockDim.x + threadIdx.x;
  int slot = gtid >> 3;
  if (slot >= S_) return;
  int l = gtid & 7;
  int src, dstn;
  if (slot < E_) { src = srclist[slot]; dstn = dstlist[slot]; }
  else { src = slot - E_; dstn = src; }
  int c0 = l * 16;
  const uint4* pa = reinterpret_cast<const uint4*>(&xl[(size_t)src * F + c0]);
  const uint4* pb = reinterpret_cast<const uint4*>(&xr[(size_t)dstn * F + c0]);
  uint4 a0 = pa[0], a1 = pa[1];
  uint4 b0 = pb[0], b1 = pb[1];
  const float4* pv = reinterpret_cast<const float4*>(&att[c0]);
  float4 v0 = pv[0], v1 = pv[1], v2 = pv[2], v3 = pv[3];
  float s = 0.0f;
  CH2(a0.x, b0.x, v0.x, v0.y) CH2(a0.y, b0.y, v0.z, v0.w)
  CH2(a0.z, b0.z, v1.x, v1.y) CH2(a0.w, b0.w, v1.z, v1.w)
  CH2(a1.x, b1.x, v2.x, v2.y) CH2(a1.y, b1.y, v2.z, v2.w)
  CH2(a1.z, b1.z, v3.x, v3.y) CH2(a1.w, b1.w, v3.z, v3.w)
  s += __shfl_xor(s, 1);
  s += __shfl_xor(s, 2);
  s += __shfl_xor(s, 4);
  if (l == 0) p2[slot] = __expf(s);
}

// ---------------- node aggregation conv1 (shuffle-free) + ELU -------------
__global__ __launch_bounds__(256) void node_agg1(
    const unsigned short* __restrict__ xl, const int* __restrict__ rowptr,
    const int* __restrict__ srclist, const float* __restrict__ p1,
    const float* __restrict__ bias, float* __restrict__ out, int Nn, int E_)
{
  int wid = (blockIdx.x * blockDim.x + threadIdx.x) >> 6;
  int lane = threadIdx.x & 63;
  if (wid >= Nn) return;
  const int n = wid;
  const int c0 = lane * 2;
  const int h = lane >> 3;
  unsigned int us = *reinterpret_cast<const unsigned int*>(&xl[(size_t)n * F + c0]);
  float xs0 = bflo(us), xs1 = bfhi(us);
  float pv = p1[((size_t)(E_ + n)) * 8 + h];   // self-loop
  float den = pv, a0 = pv * xs0, a1 = pv * xs1;
  const int beg = rowptr[n], end = rowptr[n + 1];
  #pragma unroll 4
  for (int i = beg; i < end; ++i) {
    int s = srclist[i];
    float pe = p1[(size_t)i * 8 + h];
    unsigned int uv = *reinterpret_cast<const unsigned int*>(&xl[(size_t)s * F + c0]);
    den += pe;
    a0 = fmaf(pe, bflo(uv), a0);
    a1 = fmaf(pe, bfhi(uv), a1);
  }
  float inv = 1.0f / den;
  float o0 = a0 * inv + bias[c0];
  float o1 = a1 * inv + bias[c0 + 1];
  o0 = o0 > 0.f ? o0 : (__expf(o0) - 1.0f);
  o1 = o1 > 0.f ? o1 : (__expf(o1) - 1.0f);
  *reinterpret_cast<float2*>(&out[(size_t)n * F + c0]) = make_float2(o0, o1);
}

// ---------------- node aggregation conv2 (shuffle-free) + ELU -------------
__global__ __launch_bounds__(256) void node_agg2(
    const unsigned short* __restrict__ xl, const int* __restrict__ rowptr,
    const int* __restrict__ srclist, const float* __restrict__ p2,
    const float* __restrict__ bias, float* __restrict__ out, int Nn, int E_)
{
  int wid = (blockIdx.x * blockDim.x + threadIdx.x) >> 6;
  int lane = threadIdx.x & 63;
  if (wid >= Nn) return;
  const int n = wid;
  const int c0 = lane * 2;
  unsigned int us = *reinterpret_cast<const unsigned int*>(&xl[(size_t)n * F + c0]);
  float xs0 = bflo(us), xs1 = bfhi(us);
  float pv = p2[E_ + n];                       // self-loop
  float den = pv, a0 = pv * xs0, a1 = pv * xs1;
  const int beg = rowptr[n], end = rowptr[n + 1];
  #pragma unroll 4
  for (int i = beg; i < end; ++i) {
    int s = srclist[i];
    float pe = p2[i];
    unsigned int uv = *reinterpret_cast<const unsigned int*>(&xl[(size_t)s * F + c0]);
    den += pe;
    a0 = fmaf(pe, bflo(uv), a0);
    a1 = fmaf(pe, bfhi(uv), a1);
  }
  float inv = 1.0f / den;
  float o0 = a0 * inv + bias[c0];
  float o1 = a1 * inv + bias[c0 + 1];
  o0 = o0 > 0.f ? o0 : (__expf(o0) - 1.0f);
  o1 = o1 > 0.f ? o1 : (__expf(o1) - 1.0f);
  *reinterpret_cast<float2*>(&out[(size_t)n * F + c0]) = make_float2(o0, o1);
}

// ---------------- chunked mean pool stage 1 (batch sorted) ----------------
#define PB 128  // nodes per block
__global__ __launch_bounds__(128) void k_pool1(
    const float* __restrict__ h2, const int* __restrict__ batch,
    float* __restrict__ sums, int Nn)
{
  int c = threadIdx.x;             // channel
  int n0 = blockIdx.x * PB;
  if (n0 >= Nn) return;
  int n1 = n0 + PB; if (n1 > Nn) n1 = Nn;
  int gcur = batch[n0];
  float acc = 0.f;
  for (int n = n0; n < n1; ++n) {
    int g = batch[n];
    if (g != gcur) { atomicAdd(&sums[gcur * F + c], acc); acc = 0.f; gcur = g; }
    acc += h2[(size_t)n * F + c];
  }
  atomicAdd(&sums[gcur * F + c], acc);
}

// ---------------- per-graph counts (batch sorted; binary search) ----------
__global__ void k_counts(const int* __restrict__ batch, float* __restrict__ gcnt, int Nn) {
  int g = threadIdx.x;
  if (g >= NG) return;
  int lo = 0, hi = Nn;
  while (lo < hi) { int mid = (lo + hi) >> 1; if (batch[mid] < g) lo = mid + 1; else hi = mid; }
  int lo2 = lo, hi2 = Nn;
  while (lo2 < hi2) { int mid = (lo2 + hi2) >> 1; if (batch[mid] < g + 1) lo2 = mid + 1; else hi2 = mid; }
  int cnt = lo2 - lo;
  gcnt[g] = (float)(cnt > 1 ? cnt : 1);
}

// ---------------- final: out = (sums/cnt) @ W3 + b3 ----------------
__global__ void k_final(const float* __restrict__ sums, const float* __restrict__ gcnt,
                        const float* __restrict__ W3, const float* __restrict__ b3,
                        float* __restrict__ out)
{
  int t = blockIdx.x * blockDim.x + threadIdx.x;
  if (t >= NG * NCLS) return;
  int g = t / NCLS, k = t % NCLS;
  float acc = 0.f;
  for (int cc = 0; cc < F; ++cc) acc = fmaf(sums[g * F + cc], W3[cc * NCLS + k], acc);
  out[t] = acc / gcnt[g] + b3[k];
}

extern "C" void kernel_launch(void* const* d_in, const int* in_sizes, int n_in,
                              void* d_out, int out_size, void* d_ws, size_t ws_size,
                              hipStream_t stream)
{
  const float* x     = (const float*)d_in[0];
  const int*   ei    = (const int*)d_in[1];
  const int*   batch = (const int*)d_in[2];
  const float* W1l = (const float*)d_in[3];
  const float* b1l = (const float*)d_in[4];
  const float* W1r = (const float*)d_in[5];
  const float* b1r = (const float*)d_in[6];
  const float* att1  = (const float*)d_in[7];
  const float* bias1 = (const float*)d_in[8];
  const float* W2l = (const float*)d_in[9];
  const float* b2l = (const float*)d_in[10];
  const float* W2r = (const float*)d_in[11];
  const float* b2r = (const float*)d_in[12];
  const float* att2  = (const float*)d_in[13];
  const float* bias2 = (const float*)d_in[14];
  const float* W3 = (const float*)d_in[15];
  const float* b3 = (const float*)d_in[16];

  const int Nn = in_sizes[0] / F;
  const int Ee = in_sizes[1] / 2;
  const int Ss = Ee + Nn;   // edge slots + self-loop slots
  const int* srcp = ei;
  const int* dstp = ei + Ee;

  char* ws = (char*)d_ws;
  size_t off = 0;
  auto alloc = [&](size_t bytes) -> void* {
    void* p = ws + off;
    off = (off + bytes + 255) & ~size_t(255);
    return p;
  };
  unsigned short* xl = (unsigned short*)alloc((size_t)Nn * F * 2);
  unsigned short* xr = (unsigned short*)alloc((size_t)Nn * F * 2);
  float* h12     = (float*)alloc((size_t)Nn * F * 4);   // h1, then reused as h2
  float* p12     = (float*)alloc((size_t)Ss * 8 * 4);   // p1 [S][8]; p2 uses first S
  int*   cnt     = (int*)alloc((size_t)Nn * 4);         // count, later cursor
  int*   rowptr  = (int*)alloc((size_t)(Nn + 1) * 4);
  int*   srclist = (int*)alloc((size_t)Ee * 4);
  int*   dstlist = (int*)alloc((size_t)Ee * 4);
  float* sums    = (float*)alloc((size_t)(NG * F + NG) * 4);  // sums + gcnt
  float* gcnt    = sums + NG * F;
  int*   bsum    = (int*)alloc(1024);

  hipMemsetAsync(cnt, 0, (size_t)Nn * 4, stream);
  hipMemsetAsync(sums, 0, (size_t)NG * F * 4, stream);

  const int TB = 256;
  // CSR build
  k_count<<<(Ee + TB - 1) / TB, TB, 0, stream>>>(dstp, cnt, Ee);
  int nb = (Nn + 1023) / 1024;
  k_scan1<<<nb, 256, 0, stream>>>(cnt, rowptr, bsum, Nn);
  k_scan2<<<1, 64, 0, stream>>>(bsum, nb);
  k_scan3<<<(Nn + TB - 1) / TB, TB, 0, stream>>>(rowptr, bsum, Nn, Ee);
  hipMemcpyAsync(cnt, rowptr, (size_t)Nn * 4, hipMemcpyDeviceToDevice, stream);
  k_fill<<<(Ee + TB - 1) / TB, TB, 0, stream>>>(srcp, dstp, cnt, srclist, dstlist, Ee);

  int score_blocks = ((size_t)Ss * 8 + 255) / 256;   // 8 lanes per slot
  int node_blocks  = (Nn + 3) / 4;

  // conv1
  dual_gemm<<<(Nn + GR - 1) / GR, 128, 0, stream>>>(x, W1l, b1l, W1r, b1r, xl, xr, Nn);
  score1<<<score_blocks, 256, 0, stream>>>(xl, xr, srclist, dstlist, att1, p12, Ee, Ss);
  node_agg1<<<node_blocks, 256, 0, stream>>>(xl, rowptr, srclist, p12, bias1, h12, Nn, Ee);
  // conv2
  dual_gemm<<<(Nn + GR - 1) / GR, 128, 0, stream>>>(h12, W2l, b2l, W2r, b2r, xl, xr, Nn);
  score2<<<score_blocks, 256, 0, stream>>>(xl, xr, srclist, dstlist, att2, p12, Ee, Ss);
  node_agg2<<<node_blocks, 256, 0, stream>>>(xl, rowptr, srclist, p12, bias2, h12, Nn, Ee);
  // pool + head
  k_pool1<<<(Nn + PB - 1) / PB, 128, 0, stream>>>(h12, batch, sums, Nn);
  k_counts<<<1, 64, 0, stream>>>(batch, gcnt, Nn);
  k_final<<<(NG * NCLS + 255) / 256, 256, 0, stream>>>(sums, gcnt, W3, b3, (float*)d_out);
}